// Round 8
// baseline (265.072 us; speedup 1.0000x reference)
//
#include <hip/hip_runtime.h>

// ForwardKinematics, fp32: rotations (B,24,4) wxyz + positions (B,24,3)
// -> global joint positions (B,24,3). Fixed SMPL tree.
//
// Round 8: 3 threads/sample (total 3B threads -> 24 waves/CU; the 2-thr/sample
// structure hard-capped occupancy at 16 waves/CU, which rounds 6/7 showed is
// the limiter). Wave-uniform groups, each ancestor-closed with redundant
// spine recompute (VALU is ~16% busy -> redundancy free):
//   w0: joints 0..7   (8 nodes)
//   w1: joints 8..15  (16 nodes: redo 0..7)
//   w2: joints 16..23 (14 nodes: redo 0,3,6,9,13,14)
// Scattered per-thread input loads (proven cheap in r6), LDS output staging
// (pitch 19 f4/sample) + dense f4 stores (proven: WRITE == ideal 36.9 MB).
// 192 thr/block, SPB=64, LDS 19.5 KB -> 8 blocks/CU.

typedef float f32x4 __attribute__((ext_vector_type(4)));

struct M { float r0,r1,r2,r3,r4,r5,r6,r7,r8,tx,ty,tz; };

__device__ __forceinline__ M loc(f32x4 q, float px, float py, float pz) {
    float inv = rsqrtf(q.x*q.x + q.y*q.y + q.z*q.z + q.w*q.w);
    float qw = q.x*inv, qx = q.y*inv, qy = q.z*inv, qz = q.w*inv;
    float x2 = qx+qx, y2 = qy+qy, z2 = qz+qz;
    float xx = qx*x2, yy = qy*y2, zz = qz*z2;
    float xy = qx*y2, yz = qy*z2, xz = qx*z2;
    float wx = qw*x2, wy = qw*y2, wz = qw*z2;
    M m;
    m.r0 = 1.f-(yy+zz); m.r1 = xy-wz;       m.r2 = xz+wy;
    m.r3 = xy+wz;       m.r4 = 1.f-(xx+zz); m.r5 = yz-wx;
    m.r6 = xz-wy;       m.r7 = yz+wx;       m.r8 = 1.f-(xx+yy);
    m.tx = px; m.ty = py; m.tz = pz;
    return m;
}

__device__ __forceinline__ M mul(const M& a, const M& b) {
    M c;
    c.r0 = a.r0*b.r0 + a.r1*b.r3 + a.r2*b.r6;
    c.r1 = a.r0*b.r1 + a.r1*b.r4 + a.r2*b.r7;
    c.r2 = a.r0*b.r2 + a.r1*b.r5 + a.r2*b.r8;
    c.r3 = a.r3*b.r0 + a.r4*b.r3 + a.r5*b.r6;
    c.r4 = a.r3*b.r1 + a.r4*b.r4 + a.r5*b.r7;
    c.r5 = a.r3*b.r2 + a.r4*b.r5 + a.r5*b.r8;
    c.r6 = a.r6*b.r0 + a.r7*b.r3 + a.r8*b.r6;
    c.r7 = a.r6*b.r1 + a.r7*b.r4 + a.r8*b.r7;
    c.r8 = a.r6*b.r2 + a.r7*b.r5 + a.r8*b.r8;
    c.tx = a.r0*b.tx + a.r1*b.ty + a.r2*b.tz + a.tx;
    c.ty = a.r3*b.tx + a.r4*b.ty + a.r5*b.tz + a.ty;
    c.tz = a.r6*b.tx + a.r7*b.ty + a.r8*b.tz + a.tz;
    return c;
}

// Run a topo-ordered node chain; last N-NA nodes are the 8 output joints
// (consecutive joint ids), whose translations land in o[0..23].
template<int N, int NA>
__device__ __forceinline__ void run_chain(const int (&JN)[N], const int (&PI)[N],
                                          const f32x4* __restrict__ rq,
                                          const float (&pd)[72], float (&o)[24]) {
    M G[N];
#pragma unroll
    for (int i = 0; i < N; ++i) {
        const int j = JN[i];
        M L = loc(rq[j], pd[3*j], pd[3*j+1], pd[3*j+2]);
        if (PI[i] < 0) G[i] = L;
        else           G[i] = mul(G[PI[i]], L);
        if (i >= NA) {
            const int k = i - NA;
            o[3*k] = G[i].tx; o[3*k+1] = G[i].ty; o[3*k+2] = G[i].tz;
        }
    }
}

#define SPB 64   // samples per block; 192 threads = 3 waves = 3 tree groups

__global__ __launch_bounds__(192, 6) void fk_kernel(
    const f32x4* __restrict__ rot4,   // B*24 f4 (one quat per joint)
    const f32x4* __restrict__ pos4,   // B*18 f4
    f32x4*       __restrict__ out4,   // B*18 f4
    int B)
{
    __shared__ f32x4 lds[SPB * 19];   // pitch 19 f4/sample (18 data + 1 pad)

    const int t = threadIdx.x;        // 0..191
    const int g = t >> 6;             // wave id = tree group (uniform)
    const int l = t & 63;             // local sample
    const int b = blockIdx.x * SPB + l;
    const bool act = (b < B);

    float o[24];
    if (act) {
        const f32x4* rq = rot4 + (size_t)b * 24;
        const f32x4* pp = pos4 + (size_t)b * 18;
        float pd[72];                 // filled sparsely, static indices (SROA)

        if (g == 0) {
            // translations for joints 0..7 -> pos granules 0..5
#pragma unroll
            for (int m = 0; m < 6; ++m) {
                f32x4 v = pp[m];
                pd[4*m]=v.x; pd[4*m+1]=v.y; pd[4*m+2]=v.z; pd[4*m+3]=v.w;
            }
            constexpr int JN[8] = {0,1,2,3,4,5,6,7};
            constexpr int PI[8] = {-1,0,0,0,1,2,3,4};
            run_chain<8,0>(JN, PI, rq, pd, o);
        } else if (g == 1) {
            // translations for joints 0..15 -> pos granules 0..11
#pragma unroll
            for (int m = 0; m < 12; ++m) {
                f32x4 v = pp[m];
                pd[4*m]=v.x; pd[4*m+1]=v.y; pd[4*m+2]=v.z; pd[4*m+3]=v.w;
            }
            constexpr int JN[16] = {0,1,2,3,4,5,6,7,8,9,10,11,12,13,14,15};
            constexpr int PI[16] = {-1,0,0,0,1,2,3,4,5,6,7,8,9,9,9,12};
            run_chain<16,8>(JN, PI, rq, pd, o);
        } else {
            // translations for joints {0,3,6,9,13,14,16..23}
            // -> granules {0,2,4,5,6,7,9,10,11,12,13,14,15,16,17}
            constexpr int GL[15] = {0,2,4,5,6,7,9,10,11,12,13,14,15,16,17};
#pragma unroll
            for (int n = 0; n < 15; ++n) {
                const int m = GL[n];
                f32x4 v = pp[m];
                pd[4*m]=v.x; pd[4*m+1]=v.y; pd[4*m+2]=v.z; pd[4*m+3]=v.w;
            }
            constexpr int JN[14] = {0,3,6,9,13,14,16,17,18,19,20,21,22,23};
            constexpr int PI[14] = {-1,0,1,2,3,3,4,5,6,7,8,9,10,11};
            run_chain<14,6>(JN, PI, rq, pd, o);
        }

        // stage this thread's 24 output floats (joints 8g..8g+7) to LDS
        f32x4* ld = lds + l * 19 + g * 6;
#pragma unroll
        for (int m = 0; m < 6; ++m) {
            f32x4 v = {o[4*m], o[4*m+1], o[4*m+2], o[4*m+3]};
            ld[m] = v;
        }
    }
    __syncthreads();

    // Dense unload: block owns f4 [blockIdx*1152, +1152); 6 per thread.
    const size_t obase = (size_t)blockIdx.x * (SPB * 18);
    const size_t olim  = (size_t)B * 18;
#pragma unroll
    for (int i = 0; i < 6; ++i) {
        const int idx = i * 192 + t;          // 0..1151
        const int s = idx / 18, r = idx % 18; // magic-mul
        if (obase + idx < olim)
            out4[obase + idx] = lds[s * 19 + r];
    }
}

extern "C" void kernel_launch(void* const* d_in, const int* in_sizes, int n_in,
                              void* d_out, int out_size, void* d_ws, size_t ws_size,
                              hipStream_t stream) {
    const int B = out_size / 72;           // (B,24,3)
    const void* rot = nullptr;
    const void* pos = nullptr;
    for (int i = 0; i < n_in; ++i) {       // resolve by size, not order
        if      (in_sizes[i] == B * 96) rot = d_in[i];
        else if (in_sizes[i] == B * 72) pos = d_in[i];
    }
    if (!rot) rot = d_in[2];
    if (!pos) pos = d_in[1];

    const int grid = (B + SPB - 1) / SPB;  // 2048 blocks @ B=131072
    fk_kernel<<<grid, 192, 0, stream>>>(
        (const f32x4*)rot, (const f32x4*)pos, (f32x4*)d_out, B);
}